// Round 6
// baseline (335.585 us; speedup 1.0000x reference)
//
#include <hip/hip_runtime.h>

using half8   = __attribute__((ext_vector_type(8))) _Float16;
using floatx4 = __attribute__((ext_vector_type(4))) float;
using floatx2 = __attribute__((ext_vector_type(2))) float;
using short8  = __attribute__((ext_vector_type(8))) short;

// xt layout: [b 32][cchunk 8][hh 58][ww 64][slot 40] f16  (80 B per position,
// slots 32..39 zero pad -> read bank-quad (5*pos+quad)%8 is a permutation).
// hh = h+1 (rows 0,57 zero), ww = w+1 (cols 0,57..63 zero).
#define XT_ROW_ELEMS 2560                       // 64*40
#define XT_ROW_BYTES 5120
#define XT_OFF ((size_t)2 << 20)                // wre in [0, 1.18MB); xt at +2MB
#define XT_BYTES ((size_t)256 * 58 * XT_ROW_BYTES)   // 76,021,760

__device__ __forceinline__ void dma16(const void* g, void* l) {
  __builtin_amdgcn_global_load_lds(
      (const __attribute__((address_space(1))) void*)g,
      (__attribute__((address_space(3))) void*)l, 16, 0, 0);
}

// ---- prep: fused weight repack + x transpose/convert/pad ----
// blocks [0,14848): transpose one (b,cc,hh) row; blocks [14848,17152): repack
__global__ __launch_bounds__(256) void prep_kernel(
    const float* __restrict__ x, const float* __restrict__ qw,
    _Float16* __restrict__ wre, _Float16* __restrict__ xt)
{
  const int bid = blockIdx.x;
  const int t = threadIdx.x;
  if (bid >= 14848) {                           // ---- weight repack ----
    int idx = (bid - 14848) * 256 + t;          // < 9*256*256
    int c = idx & 255, co = (idx >> 8) & 255, s = idx >> 16;
    wre[idx] = (_Float16)qw[(co * 256 + c) * 9 + s];
    return;
  }
  // ---- transpose one padded row ----
  __shared__ _Float16 lt[32 * 57];              // [c32][w56 +1 pad]
  const int hh = bid % 58;
  const int bc = bid / 58;                      // b*8 + cc
  const int cc = bc & 7, b = bc >> 3;
  _Float16* dst = xt + ((size_t)bc * 58 + hh) * XT_ROW_ELEMS;
  const bool interior = (hh >= 1) && (hh <= 56);
  if (interior) {
    const int c = t >> 3, j = t & 7;            // 8 threads cover 56 w
    const float* src = x + (((size_t)(b * 256 + cc * 32 + c)) * 56 + (hh - 1)) * 56 + j * 7;
#pragma unroll
    for (int i = 0; i < 7; ++i) lt[c * 57 + j * 7 + i] = (_Float16)src[i];
  }
  __syncthreads();
  // write 320 16B-chunks (64 pos x 5 slots-of-8) coalesced
  for (int ch = t; ch < 320; ch += 256) {
    int pos = ch / 5, sl = ch - pos * 5;
    short8 v = {0, 0, 0, 0, 0, 0, 0, 0};
    if (interior && sl < 4 && pos >= 1 && pos <= 56) {
      int w = pos - 1;
#pragma unroll
      for (int i = 0; i < 8; ++i)
        v[i] = __builtin_bit_cast(short, lt[(sl * 8 + i) * 57 + w]);
    }
    *reinterpret_cast<short8*>(dst + ch * 8) = v;
  }
}

// ---- main conv v5: 3-buffer DMA pipeline, counted-vmcnt raw barriers ----
// Block: 256 thr = 4 waves; 256 cout x 112 px (2 rows x 56). Grid 896.
// Wave: 64 cout (acc[4][7] = 112 AGPR). 2 blocks/CU.
// Schedule per chunk: [s_waitcnt vmcnt(5); s_barrier] -> [issue DMA c+2]
// -> [compute c].  Chunk c's DMAs get 2 compute phases to land; c+1's 5
// DMAs stay in flight across the barrier (T4: never vmcnt(0) mid-loop).
__global__ __launch_bounds__(256, 2) void binconv_v5(
    const float* __restrict__ scale, const float* __restrict__ bias,
    const _Float16* __restrict__ wre, const _Float16* __restrict__ xt,
    float* __restrict__ out)
{
  __shared__ _Float16 xs[3 * 4 * 64 * 40];      // 3 x 20,480 B

  const int tid  = threadIdx.x;
  const int nb   = blockIdx.x;                  // (b, h-pair)
  const int b    = nb / 28;
  const int h0   = (nb % 28) * 2;
  const int wave = tid >> 6;
  const int lane = tid & 63;
  const int nl   = lane & 15;
  const int quad = lane >> 4;
  const int co_wave = wave * 64;

  int bbase[7];                                 // byte offsets, 80B/pos stride
#pragma unroll
  for (int j = 0; j < 7; ++j) {
    int n = j * 16 + nl;
    int r = (n >= 56) ? 1 : 0;
    int w = n - r * 56;
    bbase[j] = (r * 64 + w) * 80 + quad * 16;
  }

  const _Float16* aptr[4];
#pragma unroll
  for (int mi = 0; mi < 4; ++mi)
    aptr[mi] = wre + (co_wave + mi * 16 + nl) * 256 + quad * 8;

  floatx4 acc[4][7];
#pragma unroll
  for (int mi = 0; mi < 4; ++mi)
#pragma unroll
    for (int j = 0; j < 7; ++j)
      acc[mi][j] = (floatx4){0.f, 0.f, 0.f, 0.f};

  // staging: wave handles padded row hh = h0 + wave (always in-bounds 0..57)
  const char* xsrc = (const char*)(xt + ((size_t)(b * 8) * 58 + h0) * XT_ROW_ELEMS);
  const int wlane = wave * XT_ROW_BYTES + lane * 16;
  const int wldso = wave * XT_ROW_BYTES;

  // prologue: DMA chunk 0 -> buf 0, chunk 1 -> buf 1
#pragma unroll
  for (int i = 0; i < 5; ++i)
    dma16(xsrc + wlane + i * 1024, (char*)xs + wldso + i * 1024);
#pragma unroll
  for (int i = 0; i < 5; ++i)
    dma16(xsrc + (58 * XT_ROW_BYTES) + wlane + i * 1024,
          (char*)xs + 20480 + wldso + i * 1024);

  int cur = 0, nxt = 20480, nx2 = 40960;        // byte offsets, rotate mod 3
  for (int cc = 0; cc < 8; ++cc) {
    // counted-vmcnt barrier: oldest outstanding batch (chunk cc) must be
    // done in every wave; chunk cc+1's 5 DMAs stay in flight (FIFO counter:
    // any cc-DMA incomplete => outstanding > 5).
    if (cc < 7) asm volatile("s_waitcnt vmcnt(5) lgkmcnt(0)" ::: "memory");
    else        asm volatile("s_waitcnt vmcnt(0) lgkmcnt(0)" ::: "memory");
    __builtin_amdgcn_sched_barrier(0);
    __builtin_amdgcn_s_barrier();
    __builtin_amdgcn_sched_barrier(0);
    // issue chunk cc+2 into the buffer consumed in iteration cc-1
    // (safe: all waves passed the barrier above, so all reads retired)
    if (cc < 6) {
      const char* srcn = xsrc + (size_t)(cc + 2) * (58 * XT_ROW_BYTES);
#pragma unroll
      for (int i = 0; i < 5; ++i)
        dma16(srcn + wlane + i * 1024, (char*)xs + nx2 + wldso + i * 1024);
    }
    const int c0 = cc * 32;
    const char* xb = (const char*)xs + cur;
    __builtin_amdgcn_s_setprio(1);
#pragma unroll
    for (int s = 0; s < 9; ++s) {
      const int kh = s / 3, kw = s - kh * 3;
      half8 a[4];
#pragma unroll
      for (int mi = 0; mi < 4; ++mi)
        a[mi] = *reinterpret_cast<const half8*>(aptr[mi] + s * 65536 + c0);
      const int soff = (kh * 64 + kw) * 80;
#pragma unroll
      for (int j = 0; j < 7; ++j) {
        half8 bf = *reinterpret_cast<const half8*>(xb + bbase[j] + soff);
#pragma unroll
        for (int mi = 0; mi < 4; ++mi)
          acc[mi][j] = __builtin_amdgcn_mfma_f32_16x16x32_f16(a[mi], bf, acc[mi][j], 0, 0, 0);
      }
    }
    __builtin_amdgcn_s_setprio(0);
    int t_ = cur; cur = nxt; nxt = nx2; nx2 = t_;
  }

  // epilogue: C/D layout n=lane&15, m=quad*4+reg
#pragma unroll
  for (int mi = 0; mi < 4; ++mi) {
#pragma unroll
    for (int reg = 0; reg < 4; ++reg) {
      int co = co_wave + mi * 16 + quad * 4 + reg;
      float s_ = scale[co];
      float bi = bias[co];
#pragma unroll
      for (int j = 0; j < 7; ++j) {
        int n = j * 16 + nl;
        int r = (n >= 56) ? 1 : 0;
        int w = n - r * 56;
        out[(((size_t)b * 256 + co) * 56 + (h0 + r)) * 56 + w] =
            acc[mi][j][reg] * s_ + bi;
      }
    }
  }
}

// ---------------- fallback path (ws too small): fused kernel ----------------
__global__ void repack_weights(const float* __restrict__ qw,
                               _Float16* __restrict__ wre, int n) {
  int t = blockIdx.x * 256 + threadIdx.x;
  if (t >= n) return;
  int c = t & 255, co = (t >> 8) & 255, s = t >> 16;
  wre[t] = (_Float16)qw[(co * 256 + c) * 9 + s];
}

__global__ __launch_bounds__(512, 4) void binconv_fused(
    const float* __restrict__ x, const float* __restrict__ scale,
    const float* __restrict__ bias, const _Float16* __restrict__ wre,
    float* __restrict__ out)
{
  __shared__ _Float16 xs[2 * 4 * 64 * 40];
  const int tid  = threadIdx.x;
  const int nb   = blockIdx.x;
  const int b    = nb / 28;
  const int h0   = (nb % 28) * 2;
  const int wave = tid >> 6;
  const int lane = tid & 63;
  const int nl   = lane & 15;
  const int quad = lane >> 4;
  const int co_wave = wave * 32;
  {
    short8 z = {0, 0, 0, 0, 0, 0, 0, 0};
    short8* xs8 = reinterpret_cast<short8*>(xs);
#pragma unroll
    for (int i = 0; i < 5; ++i) xs8[tid + i * 512] = z;
  }
  const int r     = wave >> 1;
  const int chalf = wave & 1;
  const int sc    = lane & 15;
  const int q     = lane >> 4;
  const int ch    = chalf * 16 + sc;
  const int w0    = q * 14;
  const int h     = h0 + r - 1;
  const bool hok  = (h >= 0) && (h < 56);
  const float* xc = x + (((size_t)b * 256 + ch) * 56 + (hok ? h : 0)) * 56 + w0;
  _Float16* const wrow = xs + r * 2560 + ch;
  floatx2 va[7];
  int bbase[7];
#pragma unroll
  for (int j = 0; j < 7; ++j) {
    int n = j * 16 + nl;
    int rr = (n >= 56) ? 1 : 0;
    int w = n - rr * 56;
    bbase[j] = (rr * 64 + w) * 80 + quad * 16;
  }
  const _Float16* aptr[2];
#pragma unroll
  for (int mi = 0; mi < 2; ++mi)
    aptr[mi] = wre + (co_wave + mi * 16 + nl) * 256 + quad * 8;
  floatx4 acc[2][7];
#pragma unroll
  for (int mi = 0; mi < 2; ++mi)
#pragma unroll
    for (int j = 0; j < 7; ++j)
      acc[mi][j] = (floatx4){0.f, 0.f, 0.f, 0.f};
  __syncthreads();
  if (hok) {
#pragma unroll
    for (int i = 0; i < 7; ++i)
      va[i] = *reinterpret_cast<const floatx2*>(xc + 2 * i);
#pragma unroll
    for (int i = 0; i < 7; ++i) {
      wrow[(w0 + 2 * i + 1) * 40] = (_Float16)va[i][0];
      wrow[(w0 + 2 * i + 2) * 40] = (_Float16)va[i][1];
    }
  }
  int bufe = 0;
  for (int cc = 0; cc < 8; ++cc) {
    __syncthreads();
    if (cc < 7 && hok) {
      const float* A = xc + (size_t)(cc + 1) * 100352;
#pragma unroll
      for (int i = 0; i < 7; ++i)
        va[i] = *reinterpret_cast<const floatx2*>(A + 2 * i);
    }
    const int c0 = cc * 32;
    const char* xb = reinterpret_cast<const char*>(xs) + bufe * 2;
#pragma unroll
    for (int s = 0; s < 9; ++s) {
      const int kh = s / 3, kw = s - kh * 3;
      half8 a[2];
#pragma unroll
      for (int mi = 0; mi < 2; ++mi)
        a[mi] = *reinterpret_cast<const half8*>(aptr[mi] + s * 65536 + c0);
      const int soff = (kh * 64 + kw) * 80;
#pragma unroll
      for (int j = 0; j < 7; ++j) {
        half8 bf = *reinterpret_cast<const half8*>(xb + bbase[j] + soff);
#pragma unroll
        for (int mi = 0; mi < 2; ++mi)
          acc[mi][j] = __builtin_amdgcn_mfma_f32_16x16x32_f16(a[mi], bf, acc[mi][j], 0, 0, 0);
      }
    }
    if (cc < 7 && hok) {
      _Float16* d = wrow + (bufe ^ 10240);
#pragma unroll
      for (int i = 0; i < 7; ++i) {
        d[(w0 + 2 * i + 1) * 40] = (_Float16)va[i][0];
        d[(w0 + 2 * i + 2) * 40] = (_Float16)va[i][1];
      }
    }
    bufe ^= 10240;
  }
#pragma unroll
  for (int mi = 0; mi < 2; ++mi) {
#pragma unroll
    for (int reg = 0; reg < 4; ++reg) {
      int co = co_wave + mi * 16 + quad * 4 + reg;
      float s_ = scale[co];
      float bi = bias[co];
#pragma unroll
      for (int j = 0; j < 7; ++j) {
        int n = j * 16 + nl;
        int rr = (n >= 56) ? 1 : 0;
        int w = n - rr * 56;
        out[(((size_t)b * 256 + co) * 56 + (h0 + rr)) * 56 + w] =
            acc[mi][j][reg] * s_ + bi;
      }
    }
  }
}

extern "C" void kernel_launch(void* const* d_in, const int* in_sizes, int n_in,
                              void* d_out, int out_size, void* d_ws, size_t ws_size,
                              hipStream_t stream) {
  const float* x     = (const float*)d_in[0];   // [32,256,56,56]
  const float* scale = (const float*)d_in[1];   // [256]
  const float* qw    = (const float*)d_in[2];   // [256,256,3,3] in {-1,0,1}
  const float* bias  = (const float*)d_in[3];   // [256]
  float* out = (float*)d_out;

  _Float16* wre = (_Float16*)d_ws;

  if (ws_size >= XT_OFF + XT_BYTES) {
    _Float16* xt = (_Float16*)((char*)d_ws + XT_OFF);
    prep_kernel<<<17152, 256, 0, stream>>>(x, qw, wre, xt);
    binconv_v5<<<896, 256, 0, stream>>>(scale, bias, wre, xt, out);
  } else {
    repack_weights<<<2304, 256, 0, stream>>>(qw, wre, 9 * 256 * 256);
    binconv_fused<<<896, 512, 0, stream>>>(x, scale, bias, wre, out);
  }
}

// Round 7
// 319.914 us; speedup vs baseline: 1.0490x; 1.0490x over previous
//
#include <hip/hip_runtime.h>

using half8   = __attribute__((ext_vector_type(8))) _Float16;
using half2v  = __attribute__((ext_vector_type(2))) _Float16;
using floatx4 = __attribute__((ext_vector_type(4))) float;
using short8  = __attribute__((ext_vector_type(8))) short;
using uint4v  = __attribute__((ext_vector_type(4))) unsigned int;

// ---- weight repack: qw [co][c][3x3] f32 {-1,0,1} -> wre [s][co][c] f16 ----
__global__ void repack_weights(const float* __restrict__ qw,
                               _Float16* __restrict__ wre, int n) {
  int t = blockIdx.x * 256 + threadIdx.x;
  if (t >= n) return;
  int c = t & 255, co = (t >> 8) & 255, s = t >> 16;
  wre[t] = (_Float16)qw[(co * 256 + c) * 9 + s];
}

// cvt 16 f32 -> 16 f16 and store as 2 x b128 (32B contiguous slot range)
__device__ __forceinline__ void store16(_Float16* d, const float* sv) {
  unsigned int u[8];
#pragma unroll
  for (int i = 0; i < 8; ++i)
    u[i] = __builtin_bit_cast(unsigned int,
             __builtin_amdgcn_cvt_pkrtz(sv[2 * i], sv[2 * i + 1]));
  uint4v v0 = {u[0], u[1], u[2], u[3]};
  uint4v v1 = {u[4], u[5], u[6], u[7]};
  *reinterpret_cast<uint4v*>(d)     = v0;
  *reinterpret_cast<uint4v*>(d + 8) = v1;
}

// ---- fused conv v6: in-kernel staging with W-COALESCED loads ----
// LDS per buffer: [row 4][pos 64][slot 40] f16 (80 B per position).
// pos = w+1 (pos 0 / 57..63 zero pad); rows are padded input rows h0-1..h0+2.
// Block: 256 thr = 4 waves; 256 cout x 112 px. Wave: 64 cout (acc[4][7]).
// Staging: wave = padded row hh (input h = h0+hh-1); lane = w (56 active);
// per chunk 2 batches of 16 channels: 16 coalesced b32 row-loads (224 B per
// instruction) -> 8 cvt_pkrtz -> 2 ds_write_b128 (lane's 32 channel values
// are CONTIGUOUS in the slot layout). Batch loads issue before/mid MFMA
// phase (T14) so HBM latency hides under the 252-MFMA cluster.
__global__ __launch_bounds__(256, 2) void binconv_v6(
    const float* __restrict__ x, const float* __restrict__ scale,
    const float* __restrict__ bias, const _Float16* __restrict__ wre,
    float* __restrict__ out)
{
  __shared__ _Float16 xs[2 * 4 * 64 * 40];      // 2 x 20,480 B

  const int tid  = threadIdx.x;
  const int nb   = blockIdx.x;                  // (b, h-pair)
  const int b    = nb / 28;
  const int h0   = (nb % 28) * 2;
  const int wave = tid >> 6;
  const int lane = tid & 63;
  const int nl   = lane & 15;
  const int quad = lane >> 4;
  const int co_wave = wave * 64;

  // zero both buffers once; pad rows/cols stay zero forever
  {
    short8 z = {0, 0, 0, 0, 0, 0, 0, 0};
    short8* xs8 = reinterpret_cast<short8*>(xs);
#pragma unroll
    for (int i = 0; i < 10; ++i) xs8[tid + i * 256] = z;
  }

  // staging geometry
  const int h    = h0 + wave - 1;               // input row for padded row hh=wave
  const bool sok = (h >= 0) && (h < 56) && (lane < 56);
  const float* xrow = x + (((size_t)b * 256) * 56 + (sok ? h : 0)) * 56 + lane;
  const int wofs = wave * 2560 + (1 + lane) * 40;   // element offset in buffer

  int bbase[7];                                 // byte offsets, 80B/pos stride
#pragma unroll
  for (int j = 0; j < 7; ++j) {
    int n = j * 16 + nl;
    int r = (n >= 56) ? 1 : 0;
    int w = n - r * 56;
    bbase[j] = (r * 64 + w) * 80 + quad * 16;
  }

  const _Float16* aptr[4];
#pragma unroll
  for (int mi = 0; mi < 4; ++mi)
    aptr[mi] = wre + (co_wave + mi * 16 + nl) * 256 + quad * 8;

  floatx4 acc[4][7];
#pragma unroll
  for (int mi = 0; mi < 4; ++mi)
#pragma unroll
    for (int j = 0; j < 7; ++j)
      acc[mi][j] = (floatx4){0.f, 0.f, 0.f, 0.f};

  __syncthreads();                              // zero-fill visible

  float s0[16], s1[16];
  // prologue: stage chunk 0 (channels 0..31) -> buf 0
  if (sok) {
#pragma unroll
    for (int ci = 0; ci < 16; ++ci) s0[ci] = xrow[ci * 3136];
#pragma unroll
    for (int ci = 0; ci < 16; ++ci) s1[ci] = xrow[(16 + ci) * 3136];
    store16(xs + wofs, s0);
    store16(xs + wofs + 16, s1);
  }

  int bufel = 0;                                // element offset of read buffer
  for (int cc = 0; cc < 8; ++cc) {
    __syncthreads();                            // staged chunk cc visible
    const float* xn = xrow + (size_t)(cc + 1) * 32 * 3136;
    if (cc < 7 && sok) {                        // batch0 of chunk cc+1 (early)
#pragma unroll
      for (int ci = 0; ci < 16; ++ci) s0[ci] = xn[ci * 3136];
    }
    const int c0 = cc * 32;
    const char* xb = (const char*)xs + bufel * 2;
    _Float16* const wd = xs + (bufel ^ 10240) + wofs;

    __builtin_amdgcn_s_setprio(1);
#pragma unroll
    for (int s = 0; s < 5; ++s) {
      const int kh = s / 3, kw = s - kh * 3;
      half8 a[4];
#pragma unroll
      for (int mi = 0; mi < 4; ++mi)
        a[mi] = *reinterpret_cast<const half8*>(aptr[mi] + s * 65536 + c0);
      const int soff = (kh * 64 + kw) * 80;
#pragma unroll
      for (int j = 0; j < 7; ++j) {
        half8 bf = *reinterpret_cast<const half8*>(xb + bbase[j] + soff);
#pragma unroll
        for (int mi = 0; mi < 4; ++mi)
          acc[mi][j] = __builtin_amdgcn_mfma_f32_16x16x32_f16(a[mi], bf, acc[mi][j], 0, 0, 0);
      }
    }
    __builtin_amdgcn_s_setprio(0);
    // mid-phase: land batch0 into buf^1 (its prior readers finished before
    // this iteration's barrier), issue batch1
    if (cc < 7 && sok) {
      store16(wd, s0);
#pragma unroll
      for (int ci = 0; ci < 16; ++ci) s1[ci] = xn[(16 + ci) * 3136];
    }
    __builtin_amdgcn_s_setprio(1);
#pragma unroll
    for (int s = 5; s < 9; ++s) {
      const int kh = s / 3, kw = s - kh * 3;
      half8 a[4];
#pragma unroll
      for (int mi = 0; mi < 4; ++mi)
        a[mi] = *reinterpret_cast<const half8*>(aptr[mi] + s * 65536 + c0);
      const int soff = (kh * 64 + kw) * 80;
#pragma unroll
      for (int j = 0; j < 7; ++j) {
        half8 bf = *reinterpret_cast<const half8*>(xb + bbase[j] + soff);
#pragma unroll
        for (int mi = 0; mi < 4; ++mi)
          acc[mi][j] = __builtin_amdgcn_mfma_f32_16x16x32_f16(a[mi], bf, acc[mi][j], 0, 0, 0);
      }
    }
    __builtin_amdgcn_s_setprio(0);
    if (cc < 7 && sok) store16(wd + 16, s1);
    bufel ^= 10240;
  }

  // epilogue: C/D layout n=lane&15, m=quad*4+reg
#pragma unroll
  for (int mi = 0; mi < 4; ++mi) {
#pragma unroll
    for (int reg = 0; reg < 4; ++reg) {
      int co = co_wave + mi * 16 + quad * 4 + reg;
      float s_ = scale[co];
      float bi = bias[co];
#pragma unroll
      for (int j = 0; j < 7; ++j) {
        int n = j * 16 + nl;
        int r = (n >= 56) ? 1 : 0;
        int w = n - r * 56;
        out[(((size_t)b * 256 + co) * 56 + (h0 + r)) * 56 + w] =
            acc[mi][j][reg] * s_ + bi;
      }
    }
  }
}

extern "C" void kernel_launch(void* const* d_in, const int* in_sizes, int n_in,
                              void* d_out, int out_size, void* d_ws, size_t ws_size,
                              hipStream_t stream) {
  const float* x     = (const float*)d_in[0];   // [32,256,56,56]
  const float* scale = (const float*)d_in[1];   // [256]
  const float* qw    = (const float*)d_in[2];   // [256,256,3,3] in {-1,0,1}
  const float* bias  = (const float*)d_in[3];   // [256]
  float* out = (float*)d_out;

  _Float16* wre = (_Float16*)d_ws;              // 1,179,648 B

  repack_weights<<<2304, 256, 0, stream>>>(qw, wre, 9 * 256 * 256);
  binconv_v6<<<896, 256, 0, stream>>>(x, scale, bias, wre, out);
}